// Round 8
// baseline (1340.402 us; speedup 1.0000x reference)
//
#include <hip/hip_runtime.h>
#include <hip/hip_bf16.h>

#define ND 128
#define ED 128
#define NIN 128
#define EIN 291
#define KPAD 320   // EIN padded to multiple of 32
#define HH 64
#define TM 32      // edges per block in embed/classify MFMA kernels
#define TS 64      // edges per block in edge_step

typedef __attribute__((ext_vector_type(8))) short short8;
typedef __attribute__((ext_vector_type(4))) float float4_;

__device__ __forceinline__ unsigned short f2bf(float f)
{
    union { float f; unsigned u; } v; v.f = f;
    unsigned u = v.u;
    unsigned r = (u + 0x7FFFu + ((u >> 16) & 1u)) >> 16;  // RNE
    return (unsigned short)r;
}
__device__ __forceinline__ float bf2f(unsigned short s)
{
    union { unsigned u; float f; } v; v.u = ((unsigned)s) << 16;
    return v.f;
}

// Zero a float buffer.
__global__ __launch_bounds__(256) void zero_k(float* __restrict__ p, int n4)
{
    int idx = blockIdx.x * 256 + threadIdx.x;
    if (idx < n4) ((float4*)p)[idx] = make_float4(0.f, 0.f, 0.f, 0.f);
}

// Fused: convert fp32 accumulator -> bf16 activations, then zero the accumulator.
__global__ __launch_bounds__(256) void f2bfz_k(float* __restrict__ src,
                                               unsigned short* __restrict__ dst, int n4)
{
    int idx = blockIdx.x * 256 + threadIdx.x;
    if (idx < n4) {
        float4 v = ((const float4*)src)[idx];
        unsigned lo = (unsigned)f2bf(v.x) | ((unsigned)f2bf(v.y) << 16);
        unsigned hi = (unsigned)f2bf(v.z) | ((unsigned)f2bf(v.w) << 16);
        ((uint2*)dst)[idx] = make_uint2(lo, hi);
        ((float4*)src)[idx] = make_float4(0.f, 0.f, 0.f, 0.f);
    }
}

// One-time weight prep: transpose + fp32->bf16 (+ zero-pad K for edge-embed L1).
__global__ __launch_bounds__(256) void wprep_k(
    const float* __restrict__ mew0, const float* __restrict__ mew1, const float* __restrict__ mnw0,
    const float* __restrict__ eew0, const float* __restrict__ eew1, const float* __restrict__ cw0,
    unsigned short* __restrict__ w0T, unsigned short* __restrict__ w1T,
    unsigned short* __restrict__ wmT, unsigned short* __restrict__ w0eT,
    unsigned short* __restrict__ w1eT, unsigned short* __restrict__ cw0T)
{
    int idx = blockIdx.x * 256 + threadIdx.x;
    if (idx < 49152) {
        int c = idx / 768, k = idx % 768;
        w0T[idx] = f2bf(mew0[k * 64 + c]);
    } else if (idx < 57344) {
        int j = idx - 49152; int c = j / 64, k = j % 64;
        w1T[j] = f2bf(mew1[k * 128 + c]);
    } else if (idx < 106496) {
        int j = idx - 57344; int c = j / 384, k = j % 384;
        wmT[j] = f2bf(mnw0[k * 128 + c]);
    } else if (idx < 126976) {
        int j = idx - 106496; int c = j / KPAD, k = j % KPAD;
        w0eT[j] = (k < EIN) ? f2bf(eew0[k * 64 + c]) : (unsigned short)0;
    } else if (idx < 135168) {
        int j = idx - 126976; int c = j / 64, k = j % 64;
        w1eT[j] = f2bf(eew1[k * 128 + c]);
    } else if (idx < 143360) {
        int j = idx - 135168; int c = j / 128, k = j % 128;
        cw0T[j] = f2bf(cw0[k * 64 + c]);
    }
}

// nf0/nf = MLP(x): NIN->128 (ReLU) ->ND. One block (128 thr) per node. bf16 out.
__global__ __launch_bounds__(128) void node_embed_k(
    const float* __restrict__ x, const float* __restrict__ w0, const float* __restrict__ b0,
    const float* __restrict__ w1, const float* __restrict__ b1,
    unsigned short* __restrict__ nf0_bf, unsigned short* __restrict__ nf_bf)
{
    int node = blockIdx.x;
    int t = threadIdx.x;
    __shared__ float xin[NIN];
    __shared__ float h[128];
    xin[t] = x[node * NIN + t];
    __syncthreads();
    float acc = b0[t];
#pragma unroll 8
    for (int k = 0; k < NIN; k++) acc += xin[k] * w0[k * 128 + t];
    h[t] = fmaxf(acc, 0.f);
    __syncthreads();
    float acc2 = b1[t];
#pragma unroll 8
    for (int k = 0; k < 128; k++) acc2 += h[k] * w1[k * ND + t];
    unsigned short v = f2bf(acc2);
    nf0_bf[(size_t)node * ND + t] = v;
    nf_bf[(size_t)node * ND + t] = v;
}

// MFMA edge embed: 32 edges/block. L1 K=KPAD(320) N=64 (ReLU), L2 K=64 N=128 (no ReLU).
__global__ __launch_bounds__(256) void edge_embed_k(
    const float* __restrict__ ea,
    const unsigned short* __restrict__ w0eT, const float* __restrict__ b0,
    const unsigned short* __restrict__ w1eT, const float* __restrict__ b1,
    unsigned short* __restrict__ ef0_bf, unsigned short* __restrict__ ef_bf, int E)
{
    const int t = threadIdx.x;
    const int e0 = blockIdx.x * TM;
    __shared__ unsigned short ea_bf[TM][KPAD + 8];
    __shared__ unsigned short h_bf[TM][72];

    for (int r = 0; r < TM; r++) {
        int e = e0 + r; if (e >= E) e = E - 1;
        const float* src = ea + (size_t)e * EIN;
        for (int p = t; p < KPAD; p += 256)
            ea_bf[r][p] = (p < EIN) ? f2bf(src[p]) : (unsigned short)0;
    }
    __syncthreads();

    const int w = t >> 6, lane = t & 63, quad = lane >> 4, n16 = lane & 15;
    const int m = w & 1;

    {
        const int cb = (w >> 1) * 32;
        float4_ acc0 = {0.f, 0.f, 0.f, 0.f}, acc1 = acc0;
        const unsigned short* arow = &ea_bf[m * 16 + n16][quad * 8];
        const unsigned short* b0p = w0eT + (size_t)(cb + n16) * KPAD + quad * 8;
        const unsigned short* b1p = w0eT + (size_t)(cb + 16 + n16) * KPAD + quad * 8;
#pragma unroll 5
        for (int kc = 0; kc < 10; kc++) {
            short8 a  = *(const short8*)(arow + kc * 32);
            short8 bb0 = *(const short8*)(b0p + kc * 32);
            short8 bb1 = *(const short8*)(b1p + kc * 32);
            acc0 = __builtin_amdgcn_mfma_f32_16x16x32_bf16(a, bb0, acc0, 0, 0, 0);
            acc1 = __builtin_amdgcn_mfma_f32_16x16x32_bf16(a, bb1, acc1, 0, 0, 0);
        }
#pragma unroll
        for (int t2 = 0; t2 < 2; t2++) {
            int c = cb + t2 * 16 + n16;
            float bias = b0[c];
            float4_ ac = t2 ? acc1 : acc0;
#pragma unroll
            for (int r4 = 0; r4 < 4; r4++)
                h_bf[m * 16 + quad * 4 + r4][c] = f2bf(fmaxf(ac[r4] + bias, 0.f));
        }
    }
    __syncthreads();

    {
        const int cb = (w >> 1) * 64;
        float4_ acc[4];
#pragma unroll
        for (int q = 0; q < 4; q++) acc[q] = (float4_){0.f, 0.f, 0.f, 0.f};
#pragma unroll
        for (int kc = 0; kc < 2; kc++) {
            short8 a = *(const short8*)&h_bf[m * 16 + n16][kc * 32 + quad * 8];
#pragma unroll
            for (int tt = 0; tt < 4; tt++) {
                short8 b = *(const short8*)(w1eT + (size_t)(cb + tt * 16 + n16) * 64 + kc * 32 + quad * 8);
                acc[tt] = __builtin_amdgcn_mfma_f32_16x16x32_bf16(a, b, acc[tt], 0, 0, 0);
            }
        }
#pragma unroll
        for (int tt = 0; tt < 4; tt++) {
            int c = cb + tt * 16 + n16;
            float bias = b1[c];
#pragma unroll
            for (int r4 = 0; r4 < 4; r4++) {
                int row = m * 16 + quad * 4 + r4;
                int e = e0 + row;
                if (e < E) {
                    unsigned short v = f2bf(acc[tt][r4] + bias);
                    ef0_bf[(size_t)e * ED + c] = v;
                    ef_bf[(size_t)e * ED + c] = v;
                }
            }
        }
    }
}

// MFMA MPN step: 64 edges/block, 4 waves; each wave owns one 16-edge M-tile and
// the FULL N range. A-fragments preloaded into 24 registers (MLP=24, no dup
// across waves) and reused in the MSG phase. launch_bounds(256,3) raises the
// VGPR budget to ~170 so the preload stays in registers.
__global__ __launch_bounds__(256, 3) void edge_step_k(
    const int* __restrict__ srcj, const int* __restrict__ tgti,
    const unsigned short* __restrict__ nf0_bf, const unsigned short* __restrict__ nf_bf,
    const unsigned short* __restrict__ ef0_bf, unsigned short* __restrict__ ef_bf,
    float* __restrict__ nfn,
    const unsigned short* __restrict__ w0T, const float* __restrict__ meb0,
    const unsigned short* __restrict__ w1T, const float* __restrict__ meb1,
    const unsigned short* __restrict__ wmT, const float* __restrict__ mnb0, int E)
{
    const int t = threadIdx.x;
    const int e0 = blockIdx.x * TS;
    __shared__ unsigned short h_bf[TS][72];
    __shared__ unsigned short efn_bf[TS][136];
    __shared__ int sidx[TS];

    if (t < TS) {
        int e = e0 + t; if (e >= E) e = E - 1;
        sidx[t] = tgti[e];
    }

    const int w = t >> 6, lane = t & 63, quad = lane >> 4, n16 = lane & 15;
    const int erow = w * 16 + n16;          // this wave's edge row
    int ec = e0 + erow; if (ec >= E) ec = E - 1;
    const int ti = tgti[ec], sj = srcj[ec];

    // ---- preload all 24 A-fragments (6 segs x 4 k-chunks) ----
    short8 areg[24];
    {
        const unsigned short* pAs[6] = {
            nf0_bf + (size_t)ti * ND + quad * 8,
            nf_bf  + (size_t)ti * ND + quad * 8,
            nf0_bf + (size_t)sj * ND + quad * 8,
            nf_bf  + (size_t)sj * ND + quad * 8,
            ef0_bf + (size_t)ec * ED + quad * 8,
            ef_bf  + (size_t)ec * ED + quad * 8 };
#pragma unroll
        for (int f = 0; f < 24; f++)
            areg[f] = *(const short8*)(pAs[f >> 2] + (f & 3) * 32);
    }

    // ---- L1: K=768, N=64 (full N per wave, 4 independent acc chains) ----
    {
        float4_ acc[4];
#pragma unroll
        for (int q = 0; q < 4; q++) acc[q] = (float4_){0.f, 0.f, 0.f, 0.f};
        const unsigned short* bp = w0T + (size_t)n16 * 768 + quad * 8;
#pragma unroll
        for (int kc = 0; kc < 24; kc++) {
#pragma unroll
            for (int cb4 = 0; cb4 < 4; cb4++) {
                short8 b = *(const short8*)(bp + (size_t)cb4 * 16 * 768 + kc * 32);
                acc[cb4] = __builtin_amdgcn_mfma_f32_16x16x32_bf16(areg[kc], b, acc[cb4], 0, 0, 0);
            }
        }
#pragma unroll
        for (int cb4 = 0; cb4 < 4; cb4++) {
            int c = cb4 * 16 + n16;
            float bias = meb0[c];
#pragma unroll
            for (int r4 = 0; r4 < 4; r4++)
                h_bf[w * 16 + quad * 4 + r4][c] = f2bf(fmaxf(acc[cb4][r4] + bias, 0.f));
        }
    }
    __syncthreads();

    // ---- L2: K=64, N=128 (ReLU), ef_bf in-place + LDS copy ----
    {
        float4_ acc[8];
#pragma unroll
        for (int q = 0; q < 8; q++) acc[q] = (float4_){0.f, 0.f, 0.f, 0.f};
#pragma unroll
        for (int kc = 0; kc < 2; kc++) {
            short8 a = *(const short8*)&h_bf[w * 16 + n16][kc * 32 + quad * 8];
#pragma unroll
            for (int tt = 0; tt < 8; tt++) {
                short8 b = *(const short8*)(w1T + (size_t)(tt * 16 + n16) * 64 + kc * 32 + quad * 8);
                acc[tt] = __builtin_amdgcn_mfma_f32_16x16x32_bf16(a, b, acc[tt], 0, 0, 0);
            }
        }
#pragma unroll
        for (int tt = 0; tt < 8; tt++) {
            int c = tt * 16 + n16;
            float bias = meb1[c];
#pragma unroll
            for (int r4 = 0; r4 < 4; r4++) {
                int row = w * 16 + quad * 4 + r4;
                unsigned short v = f2bf(fmaxf(acc[tt][r4] + bias, 0.f));
                efn_bf[row][c] = v;
                int e = e0 + row;
                if (e < E) ef_bf[(size_t)e * ED + c] = v;
            }
        }
    }
    __syncthreads();

    // ---- MSG: K=384 (areg[0..7] = x_i, efn from LDS), N=128; atomic scatter ----
    {
        float4_ acc[8];
#pragma unroll
        for (int q = 0; q < 8; q++) acc[q] = (float4_){0.f, 0.f, 0.f, 0.f};
#pragma unroll
        for (int kc = 0; kc < 12; kc++) {
            short8 a;
            if (kc < 8) a = areg[kc];
            else        a = *(const short8*)&efn_bf[erow][(kc - 8) * 32 + quad * 8];
#pragma unroll
            for (int tt = 0; tt < 8; tt++) {
                short8 b = *(const short8*)(wmT + (size_t)(tt * 16 + n16) * 384 + kc * 32 + quad * 8);
                acc[tt] = __builtin_amdgcn_mfma_f32_16x16x32_bf16(a, b, acc[tt], 0, 0, 0);
            }
        }
#pragma unroll
        for (int tt = 0; tt < 8; tt++) {
            int c = tt * 16 + n16;
            float bias = mnb0[c];
#pragma unroll
            for (int r4 = 0; r4 < 4; r4++) {
                int row = w * 16 + quad * 4 + r4;
                int e = e0 + row;
                if (e < E)
                    atomicAdd(&nfn[(size_t)sidx[row] * ND + c],
                              fmaxf(acc[tt][r4] + bias, 0.f));
            }
        }
    }
}

// classify: L1 (128->64, ReLU) via MFMA with direct-global A; L2/L3 scalar fp32.
__global__ __launch_bounds__(256) void classify_k(
    const unsigned short* __restrict__ ef_bf,
    const unsigned short* __restrict__ cw0T, const float* __restrict__ cb0,
    const float* __restrict__ cw1, const float* __restrict__ cb1,
    const float* __restrict__ cw2, const float* __restrict__ cb2,
    float* __restrict__ out, int E)
{
    const int t = threadIdx.x;
    const int e0 = blockIdx.x * TM;
    __shared__ unsigned short h0_bf[TM][72];
    __shared__ float h1[TM][33];

    const int w = t >> 6, lane = t & 63, quad = lane >> 4, n16 = lane & 15;
    const int m = w & 1;
    const int erow = m * 16 + n16;
    int ec = e0 + erow; if (ec >= E) ec = E - 1;
    const unsigned short* pa = ef_bf + (size_t)ec * ED + quad * 8;

    {
        const int cb = (w >> 1) * 32;
        float4_ acc0 = {0.f, 0.f, 0.f, 0.f}, acc1 = acc0;
        const unsigned short* b0p = cw0T + (size_t)(cb + n16) * 128 + quad * 8;
        const unsigned short* b1p = b0p + (size_t)16 * 128;
#pragma unroll
        for (int kc = 0; kc < 4; kc++) {
            short8 a  = *(const short8*)(pa + kc * 32);
            short8 bb0 = *(const short8*)(b0p + kc * 32);
            short8 bb1 = *(const short8*)(b1p + kc * 32);
            acc0 = __builtin_amdgcn_mfma_f32_16x16x32_bf16(a, bb0, acc0, 0, 0, 0);
            acc1 = __builtin_amdgcn_mfma_f32_16x16x32_bf16(a, bb1, acc1, 0, 0, 0);
        }
#pragma unroll
        for (int t2 = 0; t2 < 2; t2++) {
            int c = cb + t2 * 16 + n16;
            float bias = cb0[c];
            float4_ ac = t2 ? acc1 : acc0;
#pragma unroll
            for (int r4 = 0; r4 < 4; r4++)
                h0_bf[m * 16 + quad * 4 + r4][c] = f2bf(fmaxf(ac[r4] + bias, 0.f));
        }
    }
    __syncthreads();

    {
        int c = t & 31;
        int rbase = (t >> 5) * 4;
#pragma unroll
        for (int q = 0; q < 4; q++) {
            int r = rbase + q;
            float acc = cb1[c];
#pragma unroll 8
            for (int k = 0; k < 64; k++) acc += bf2f(h0_bf[r][k]) * cw1[k * 32 + c];
            h1[r][c] = fmaxf(acc, 0.f);
        }
    }
    __syncthreads();

    if (t < TM) {
        int e = e0 + t;
        if (e < E) {
            float a = cb2[0];
#pragma unroll
            for (int k = 0; k < 32; k++) a += h1[t][k] * cw2[k];
            out[e] = a;
        }
    }
}

extern "C" void kernel_launch(void* const* d_in, const int* in_sizes, int n_in,
                              void* d_out, int out_size, void* d_ws, size_t ws_size,
                              hipStream_t stream)
{
    const float* x    = (const float*)d_in[0];
    const float* ea   = (const float*)d_in[1];
    const int*   eidx = (const int*)d_in[2];
    const float* new0 = (const float*)d_in[3];  const float* neb0 = (const float*)d_in[4];
    const float* new1 = (const float*)d_in[5];  const float* neb1 = (const float*)d_in[6];
    const float* eew0 = (const float*)d_in[7];  const float* eeb0 = (const float*)d_in[8];
    const float* eew1 = (const float*)d_in[9];  const float* eeb1 = (const float*)d_in[10];
    const float* mew0 = (const float*)d_in[11]; const float* meb0 = (const float*)d_in[12];
    const float* mew1 = (const float*)d_in[13]; const float* meb1 = (const float*)d_in[14];
    const float* mnw0 = (const float*)d_in[15]; const float* mnb0 = (const float*)d_in[16];
    const float* cw0  = (const float*)d_in[17]; const float* cb0  = (const float*)d_in[18];
    const float* cw1  = (const float*)d_in[19]; const float* cb1  = (const float*)d_in[20];
    const float* cw2  = (const float*)d_in[21]; const float* cb2  = (const float*)d_in[22];

    const int N = in_sizes[0] / NIN;   // 20000
    const int E = in_sizes[2] / 2;     // 100000
    const int* srcj = eidx;            // edge_index[0] = j (source)
    const int* tgti = eidx + E;        // edge_index[1] = i (target)

    char* wsb = (char*)d_ws;
    float* nfn = (float*)wsb;                               // N*ND fp32 accum
    unsigned short* nf0_bf = (unsigned short*)(nfn + (size_t)N * ND);
    unsigned short* nf_bf  = nf0_bf + (size_t)N * ND;
    unsigned short* ef0_bf = nf_bf + (size_t)N * ND;
    unsigned short* ef_bf  = ef0_bf + (size_t)E * ED;
    unsigned short* w0T  = ef_bf + (size_t)E * ED;          // [64][768]
    unsigned short* w1T  = w0T + 49152;                     // [128][64]
    unsigned short* wmT  = w1T + 8192;                      // [128][384]
    unsigned short* w0eT = wmT + 49152;                     // [64][KPAD]
    unsigned short* w1eT = w0eT + 64 * KPAD;                // [128][64]
    unsigned short* cw0T = w1eT + 8192;                     // [64][128]

    const int eblocks32 = (E + TM - 1) / TM;
    const int eblocks64 = (E + TS - 1) / TS;

    wprep_k<<<(143360 + 255) / 256, 256, 0, stream>>>(mew0, mew1, mnw0, eew0, eew1, cw0,
                                                      w0T, w1T, wmT, w0eT, w1eT, cw0T);
    node_embed_k<<<N, 128, 0, stream>>>(x, new0, neb0, new1, neb1, nf0_bf, nf_bf);
    edge_embed_k<<<eblocks32, 256, 0, stream>>>(ea, w0eT, eeb0, w1eT, eeb1,
                                                ef0_bf, ef_bf, E);

    const int n4 = (N * ND) / 4;
    const int zgrid = (n4 + 255) / 256;
    zero_k<<<zgrid, 256, 0, stream>>>(nfn, n4);

    for (int s = 0; s < 4; s++) {
        edge_step_k<<<eblocks64, 256, 0, stream>>>(srcj, tgti, nf0_bf, nf_bf,
                                                   ef0_bf, ef_bf, nfn,
                                                   w0T, meb0, w1T, meb1, wmT, mnb0, E);
        f2bfz_k<<<zgrid, 256, 0, stream>>>(nfn, nf_bf, n4);
    }

    classify_k<<<eblocks32, 256, 0, stream>>>(ef_bf, cw0T, cb0, cw1, cb1, cw2, cb2,
                                              (float*)d_out, E);
}

// Round 9
// 978.160 us; speedup vs baseline: 1.3703x; 1.3703x over previous
//
#include <hip/hip_runtime.h>
#include <hip/hip_bf16.h>

#define ND 128
#define ED 128
#define NIN 128
#define EIN 291
#define KPAD 320   // EIN padded to multiple of 32
#define HH 64
#define TM 32      // edges per block in embed/classify MFMA kernels
#define TS 32      // edges per block in edge_step

typedef __attribute__((ext_vector_type(8))) short short8;
typedef __attribute__((ext_vector_type(4))) float float4_;

__device__ __forceinline__ unsigned short f2bf(float f)
{
    union { float f; unsigned u; } v; v.f = f;
    unsigned u = v.u;
    unsigned r = (u + 0x7FFFu + ((u >> 16) & 1u)) >> 16;  // RNE
    return (unsigned short)r;
}
__device__ __forceinline__ float bf2f(unsigned short s)
{
    union { unsigned u; float f; } v; v.u = ((unsigned)s) << 16;
    return v.f;
}

// Zero a float buffer.
__global__ __launch_bounds__(256) void zero_k(float* __restrict__ p, int n4)
{
    int idx = blockIdx.x * 256 + threadIdx.x;
    if (idx < n4) ((float4*)p)[idx] = make_float4(0.f, 0.f, 0.f, 0.f);
}

// Fused: convert fp32 accumulator -> bf16 activations, then zero the accumulator.
__global__ __launch_bounds__(256) void f2bfz_k(float* __restrict__ src,
                                               unsigned short* __restrict__ dst, int n4)
{
    int idx = blockIdx.x * 256 + threadIdx.x;
    if (idx < n4) {
        float4 v = ((const float4*)src)[idx];
        unsigned lo = (unsigned)f2bf(v.x) | ((unsigned)f2bf(v.y) << 16);
        unsigned hi = (unsigned)f2bf(v.z) | ((unsigned)f2bf(v.w) << 16);
        ((uint2*)dst)[idx] = make_uint2(lo, hi);
        ((float4*)src)[idx] = make_float4(0.f, 0.f, 0.f, 0.f);
    }
}

// One-time weight prep: transpose + fp32->bf16 (+ zero-pad K for edge-embed L1).
__global__ __launch_bounds__(256) void wprep_k(
    const float* __restrict__ mew0, const float* __restrict__ mew1, const float* __restrict__ mnw0,
    const float* __restrict__ eew0, const float* __restrict__ eew1, const float* __restrict__ cw0,
    unsigned short* __restrict__ w0T, unsigned short* __restrict__ w1T,
    unsigned short* __restrict__ wmT, unsigned short* __restrict__ w0eT,
    unsigned short* __restrict__ w1eT, unsigned short* __restrict__ cw0T)
{
    int idx = blockIdx.x * 256 + threadIdx.x;
    if (idx < 49152) {
        int c = idx / 768, k = idx % 768;
        w0T[idx] = f2bf(mew0[k * 64 + c]);
    } else if (idx < 57344) {
        int j = idx - 49152; int c = j / 64, k = j % 64;
        w1T[j] = f2bf(mew1[k * 128 + c]);
    } else if (idx < 106496) {
        int j = idx - 57344; int c = j / 384, k = j % 384;
        wmT[j] = f2bf(mnw0[k * 128 + c]);
    } else if (idx < 126976) {
        int j = idx - 106496; int c = j / KPAD, k = j % KPAD;
        w0eT[j] = (k < EIN) ? f2bf(eew0[k * 64 + c]) : (unsigned short)0;
    } else if (idx < 135168) {
        int j = idx - 126976; int c = j / 64, k = j % 64;
        w1eT[j] = f2bf(eew1[k * 128 + c]);
    } else if (idx < 143360) {
        int j = idx - 135168; int c = j / 128, k = j % 128;
        cw0T[j] = f2bf(cw0[k * 64 + c]);
    }
}

// nf0/nf = MLP(x): NIN->128 (ReLU) ->ND. One block (128 thr) per node. bf16 out.
__global__ __launch_bounds__(128) void node_embed_k(
    const float* __restrict__ x, const float* __restrict__ w0, const float* __restrict__ b0,
    const float* __restrict__ w1, const float* __restrict__ b1,
    unsigned short* __restrict__ nf0_bf, unsigned short* __restrict__ nf_bf)
{
    int node = blockIdx.x;
    int t = threadIdx.x;
    __shared__ float xin[NIN];
    __shared__ float h[128];
    xin[t] = x[node * NIN + t];
    __syncthreads();
    float acc = b0[t];
#pragma unroll 8
    for (int k = 0; k < NIN; k++) acc += xin[k] * w0[k * 128 + t];
    h[t] = fmaxf(acc, 0.f);
    __syncthreads();
    float acc2 = b1[t];
#pragma unroll 8
    for (int k = 0; k < 128; k++) acc2 += h[k] * w1[k * ND + t];
    unsigned short v = f2bf(acc2);
    nf0_bf[(size_t)node * ND + t] = v;
    nf_bf[(size_t)node * ND + t] = v;
}

// MFMA edge embed: 32 edges/block. L1 K=KPAD(320) N=64 (ReLU), L2 K=64 N=128 (no ReLU).
__global__ __launch_bounds__(256) void edge_embed_k(
    const float* __restrict__ ea,
    const unsigned short* __restrict__ w0eT, const float* __restrict__ b0,
    const unsigned short* __restrict__ w1eT, const float* __restrict__ b1,
    unsigned short* __restrict__ ef0_bf, unsigned short* __restrict__ ef_bf, int E)
{
    const int t = threadIdx.x;
    const int e0 = blockIdx.x * TM;
    __shared__ unsigned short ea_bf[TM][KPAD + 8];
    __shared__ unsigned short h_bf[TM][72];

    for (int r = 0; r < TM; r++) {
        int e = e0 + r; if (e >= E) e = E - 1;
        const float* src = ea + (size_t)e * EIN;
        for (int p = t; p < KPAD; p += 256)
            ea_bf[r][p] = (p < EIN) ? f2bf(src[p]) : (unsigned short)0;
    }
    __syncthreads();

    const int w = t >> 6, lane = t & 63, quad = lane >> 4, n16 = lane & 15;
    const int m = w & 1;

    {
        const int cb = (w >> 1) * 32;
        float4_ acc0 = {0.f, 0.f, 0.f, 0.f}, acc1 = acc0;
        const unsigned short* arow = &ea_bf[m * 16 + n16][quad * 8];
        const unsigned short* b0p = w0eT + (size_t)(cb + n16) * KPAD + quad * 8;
        const unsigned short* b1p = w0eT + (size_t)(cb + 16 + n16) * KPAD + quad * 8;
#pragma unroll 5
        for (int kc = 0; kc < 10; kc++) {
            short8 a  = *(const short8*)(arow + kc * 32);
            short8 bb0 = *(const short8*)(b0p + kc * 32);
            short8 bb1 = *(const short8*)(b1p + kc * 32);
            acc0 = __builtin_amdgcn_mfma_f32_16x16x32_bf16(a, bb0, acc0, 0, 0, 0);
            acc1 = __builtin_amdgcn_mfma_f32_16x16x32_bf16(a, bb1, acc1, 0, 0, 0);
        }
#pragma unroll
        for (int t2 = 0; t2 < 2; t2++) {
            int c = cb + t2 * 16 + n16;
            float bias = b0[c];
            float4_ ac = t2 ? acc1 : acc0;
#pragma unroll
            for (int r4 = 0; r4 < 4; r4++)
                h_bf[m * 16 + quad * 4 + r4][c] = f2bf(fmaxf(ac[r4] + bias, 0.f));
        }
    }
    __syncthreads();

    {
        const int cb = (w >> 1) * 64;
        float4_ acc[4];
#pragma unroll
        for (int q = 0; q < 4; q++) acc[q] = (float4_){0.f, 0.f, 0.f, 0.f};
#pragma unroll
        for (int kc = 0; kc < 2; kc++) {
            short8 a = *(const short8*)&h_bf[m * 16 + n16][kc * 32 + quad * 8];
#pragma unroll
            for (int tt = 0; tt < 4; tt++) {
                short8 b = *(const short8*)(w1eT + (size_t)(cb + tt * 16 + n16) * 64 + kc * 32 + quad * 8);
                acc[tt] = __builtin_amdgcn_mfma_f32_16x16x32_bf16(a, b, acc[tt], 0, 0, 0);
            }
        }
#pragma unroll
        for (int tt = 0; tt < 4; tt++) {
            int c = cb + tt * 16 + n16;
            float bias = b1[c];
#pragma unroll
            for (int r4 = 0; r4 < 4; r4++) {
                int row = m * 16 + quad * 4 + r4;
                int e = e0 + row;
                if (e < E) {
                    unsigned short v = f2bf(acc[tt][r4] + bias);
                    ef0_bf[(size_t)e * ED + c] = v;
                    ef_bf[(size_t)e * ED + c] = v;
                }
            }
        }
    }
}

// MFMA MPN step: 32 edges/block, 4 waves. B-weights staged in padded LDS (five
// <=51.2KB phases through one reused region; pitches are 4 mod 32 dwords ->
// uniform 8 dw/bank, the b128 minimum). A-fragments direct from global.
// Wave w: M-tile (w&1) (16 edges), N-half (w>>1).
__global__ __launch_bounds__(256, 2) void edge_step_k(
    const int* __restrict__ srcj, const int* __restrict__ tgti,
    const unsigned short* __restrict__ nf0_bf, const unsigned short* __restrict__ nf_bf,
    const unsigned short* __restrict__ ef0_bf, unsigned short* __restrict__ ef_bf,
    float* __restrict__ nfn,
    const unsigned short* __restrict__ w0T, const float* __restrict__ meb0,
    const unsigned short* __restrict__ w1T, const float* __restrict__ meb1,
    const unsigned short* __restrict__ wmT, const float* __restrict__ mnb0, int E)
{
    const int t = threadIdx.x;
    const int e0 = blockIdx.x * TS;
    __shared__ unsigned short wreg[25600];          // 51.2 KB staging region
    __shared__ unsigned short h_bf[TS][72];         // pitch 72 (36 dw, %32=4)
    __shared__ unsigned short efn_bf[TS][136];      // pitch 136 (68 dw, %32=4)
    __shared__ int sidx[TS];

    if (t < TS) { int e = e0 + t; if (e >= E) e = E - 1; sidx[t] = tgti[e]; }

    const int w = t >> 6, lane = t & 63, quad = lane >> 4, n16 = lane & 15;
    const int m = w & 1, nh = w >> 1;
    const int erow = m * 16 + n16;
    int ec = e0 + erow; if (ec >= E) ec = E - 1;
    const int ti = tgti[ec], sj = srcj[ec];

    // preload 24 A-fragments (6 segs x 4 k-chunks); overlaps first staging
    short8 areg[24];
    {
        const unsigned short* pAs[6] = {
            nf0_bf + (size_t)ti * ND + quad * 8,
            nf_bf  + (size_t)ti * ND + quad * 8,
            nf0_bf + (size_t)sj * ND + quad * 8,
            nf_bf  + (size_t)sj * ND + quad * 8,
            ef0_bf + (size_t)ec * ED + quad * 8,
            ef_bf  + (size_t)ec * ED + quad * 8 };
#pragma unroll
        for (int f = 0; f < 24; f++)
            areg[f] = *(const short8*)(pAs[f >> 2] + (f & 3) * 32);
    }

    // ---- L1: K=768 in two staged halves; wave: 16 edges x 32 cols ----
    float4_ accL[2];
    accL[0] = (float4_){0.f, 0.f, 0.f, 0.f}; accL[1] = accL[0];
#pragma unroll
    for (int hf = 0; hf < 2; hf++) {
        // stage w0 half hf: 64 rows x 384 shorts -> wreg pitch 392
#pragma unroll
        for (int it = 0; it < 12; it++) {
            int idx = it * 256 + t;
            int c = idx / 48, k8 = idx % 48;
            *(short8*)&wreg[c * 392 + k8 * 8] =
                *(const short8*)&w0T[c * 768 + hf * 384 + k8 * 8];
        }
        __syncthreads();
#pragma unroll
        for (int kc = 0; kc < 12; kc++) {
#pragma unroll
            for (int tt = 0; tt < 2; tt++) {
                short8 b = *(const short8*)&wreg[(nh * 32 + tt * 16 + n16) * 392 + kc * 32 + quad * 8];
                accL[tt] = __builtin_amdgcn_mfma_f32_16x16x32_bf16(areg[hf * 12 + kc], b, accL[tt], 0, 0, 0);
            }
        }
        __syncthreads();   // done reading this half before restage
    }
#pragma unroll
    for (int tt = 0; tt < 2; tt++) {
        int c = nh * 32 + tt * 16 + n16;
        float bias = meb0[c];
#pragma unroll
        for (int r4 = 0; r4 < 4; r4++)
            h_bf[m * 16 + quad * 4 + r4][c] = f2bf(fmaxf(accL[tt][r4] + bias, 0.f));
    }

    // ---- stage w1 (128 rows x 64 shorts -> pitch 72), then L2: K=64, N-half ----
#pragma unroll
    for (int it = 0; it < 4; it++) {
        int idx = it * 256 + t;
        int c = idx / 8, k8 = idx % 8;
        *(short8*)&wreg[c * 72 + k8 * 8] = *(const short8*)&w1T[c * 64 + k8 * 8];
    }
    __syncthreads();
    {
        float4_ acc[4];
#pragma unroll
        for (int q = 0; q < 4; q++) acc[q] = (float4_){0.f, 0.f, 0.f, 0.f};
#pragma unroll
        for (int kc = 0; kc < 2; kc++) {
            short8 a = *(const short8*)&h_bf[m * 16 + n16][kc * 32 + quad * 8];
#pragma unroll
            for (int tt = 0; tt < 4; tt++) {
                short8 b = *(const short8*)&wreg[(nh * 64 + tt * 16 + n16) * 72 + kc * 32 + quad * 8];
                acc[tt] = __builtin_amdgcn_mfma_f32_16x16x32_bf16(a, b, acc[tt], 0, 0, 0);
            }
        }
#pragma unroll
        for (int tt = 0; tt < 4; tt++) {
            int c = nh * 64 + tt * 16 + n16;
            float bias = meb1[c];
#pragma unroll
            for (int r4 = 0; r4 < 4; r4++) {
                int row = m * 16 + quad * 4 + r4;
                unsigned short v = f2bf(fmaxf(acc[tt][r4] + bias, 0.f));
                efn_bf[row][c] = v;
                int e = e0 + row;
                if (e < E) ef_bf[(size_t)e * ED + c] = v;
            }
        }
    }
    __syncthreads();   // efn cross-wave + region reuse

    // ---- MSG: K=384 in two staged halves (wm 128 rows x 192 -> pitch 200) ----
    float4_ accM[4];
#pragma unroll
    for (int q = 0; q < 4; q++) accM[q] = (float4_){0.f, 0.f, 0.f, 0.f};
#pragma unroll
    for (int hf = 0; hf < 2; hf++) {
#pragma unroll
        for (int it = 0; it < 12; it++) {
            int idx = it * 256 + t;
            int c = idx / 24, k8 = idx % 24;
            *(short8*)&wreg[c * 200 + k8 * 8] =
                *(const short8*)&wmT[c * 384 + hf * 192 + k8 * 8];
        }
        __syncthreads();
#pragma unroll
        for (int kc = 0; kc < 6; kc++) {
            int kk = hf * 6 + kc;
            short8 a;
            if (kk < 8) a = areg[kk];
            else        a = *(const short8*)&efn_bf[erow][(kk - 8) * 32 + quad * 8];
#pragma unroll
            for (int tt = 0; tt < 4; tt++) {
                short8 b = *(const short8*)&wreg[(nh * 64 + tt * 16 + n16) * 200 + kc * 32 + quad * 8];
                accM[tt] = __builtin_amdgcn_mfma_f32_16x16x32_bf16(a, b, accM[tt], 0, 0, 0);
            }
        }
        __syncthreads();
    }
#pragma unroll
    for (int tt = 0; tt < 4; tt++) {
        int c = nh * 64 + tt * 16 + n16;
        float bias = mnb0[c];
#pragma unroll
        for (int r4 = 0; r4 < 4; r4++) {
            int row = m * 16 + quad * 4 + r4;
            int e = e0 + row;
            if (e < E)
                atomicAdd(&nfn[(size_t)sidx[row] * ND + c],
                          fmaxf(accM[tt][r4] + bias, 0.f));
        }
    }
}

// classify: L1 (128->64, ReLU) via MFMA with direct-global A; L2/L3 scalar fp32.
__global__ __launch_bounds__(256) void classify_k(
    const unsigned short* __restrict__ ef_bf,
    const unsigned short* __restrict__ cw0T, const float* __restrict__ cb0,
    const float* __restrict__ cw1, const float* __restrict__ cb1,
    const float* __restrict__ cw2, const float* __restrict__ cb2,
    float* __restrict__ out, int E)
{
    const int t = threadIdx.x;
    const int e0 = blockIdx.x * TM;
    __shared__ unsigned short h0_bf[TM][72];
    __shared__ float h1[TM][33];

    const int w = t >> 6, lane = t & 63, quad = lane >> 4, n16 = lane & 15;
    const int m = w & 1;
    const int erow = m * 16 + n16;
    int ec = e0 + erow; if (ec >= E) ec = E - 1;
    const unsigned short* pa = ef_bf + (size_t)ec * ED + quad * 8;

    {
        const int cb = (w >> 1) * 32;
        float4_ acc0 = {0.f, 0.f, 0.f, 0.f}, acc1 = acc0;
        const unsigned short* b0p = cw0T + (size_t)(cb + n16) * 128 + quad * 8;
        const unsigned short* b1p = b0p + (size_t)16 * 128;
#pragma unroll
        for (int kc = 0; kc < 4; kc++) {
            short8 a  = *(const short8*)(pa + kc * 32);
            short8 bb0 = *(const short8*)(b0p + kc * 32);
            short8 bb1 = *(const short8*)(b1p + kc * 32);
            acc0 = __builtin_amdgcn_mfma_f32_16x16x32_bf16(a, bb0, acc0, 0, 0, 0);
            acc1 = __builtin_amdgcn_mfma_f32_16x16x32_bf16(a, bb1, acc1, 0, 0, 0);
        }
#pragma unroll
        for (int t2 = 0; t2 < 2; t2++) {
            int c = cb + t2 * 16 + n16;
            float bias = cb0[c];
            float4_ ac = t2 ? acc1 : acc0;
#pragma unroll
            for (int r4 = 0; r4 < 4; r4++)
                h0_bf[m * 16 + quad * 4 + r4][c] = f2bf(fmaxf(ac[r4] + bias, 0.f));
        }
    }
    __syncthreads();

    {
        int c = t & 31;
        int rbase = (t >> 5) * 4;
#pragma unroll
        for (int q = 0; q < 4; q++) {
            int r = rbase + q;
            float acc = cb1[c];
#pragma unroll 8
            for (int k = 0; k < 64; k++) acc += bf2f(h0_bf[r][k]) * cw1[k * 32 + c];
            h1[r][c] = fmaxf(acc, 0.f);
        }
    }
    __syncthreads();

    if (t < TM) {
        int e = e0 + t;
        if (e < E) {
            float a = cb2[0];
#pragma unroll
            for (int k = 0; k < 32; k++) a += h1[t][k] * cw2[k];
            out[e] = a;
        }
    }
}

extern "C" void kernel_launch(void* const* d_in, const int* in_sizes, int n_in,
                              void* d_out, int out_size, void* d_ws, size_t ws_size,
                              hipStream_t stream)
{
    const float* x    = (const float*)d_in[0];
    const float* ea   = (const float*)d_in[1];
    const int*   eidx = (const int*)d_in[2];
    const float* new0 = (const float*)d_in[3];  const float* neb0 = (const float*)d_in[4];
    const float* new1 = (const float*)d_in[5];  const float* neb1 = (const float*)d_in[6];
    const float* eew0 = (const float*)d_in[7];  const float* eeb0 = (const float*)d_in[8];
    const float* eew1 = (const float*)d_in[9];  const float* eeb1 = (const float*)d_in[10];
    const float* mew0 = (const float*)d_in[11]; const float* meb0 = (const float*)d_in[12];
    const float* mew1 = (const float*)d_in[13]; const float* meb1 = (const float*)d_in[14];
    const float* mnw0 = (const float*)d_in[15]; const float* mnb0 = (const float*)d_in[16];
    const float* cw0  = (const float*)d_in[17]; const float* cb0  = (const float*)d_in[18];
    const float* cw1  = (const float*)d_in[19]; const float* cb1  = (const float*)d_in[20];
    const float* cw2  = (const float*)d_in[21]; const float* cb2  = (const float*)d_in[22];

    const int N = in_sizes[0] / NIN;   // 20000
    const int E = in_sizes[2] / 2;     // 100000
    const int* srcj = eidx;            // edge_index[0] = j (source)
    const int* tgti = eidx + E;        // edge_index[1] = i (target)

    char* wsb = (char*)d_ws;
    float* nfn = (float*)wsb;                               // N*ND fp32 accum
    unsigned short* nf0_bf = (unsigned short*)(nfn + (size_t)N * ND);
    unsigned short* nf_bf  = nf0_bf + (size_t)N * ND;
    unsigned short* ef0_bf = nf_bf + (size_t)N * ND;
    unsigned short* ef_bf  = ef0_bf + (size_t)E * ED;
    unsigned short* w0T  = ef_bf + (size_t)E * ED;          // [64][768]
    unsigned short* w1T  = w0T + 49152;                     // [128][64]
    unsigned short* wmT  = w1T + 8192;                      // [128][384]
    unsigned short* w0eT = wmT + 49152;                     // [64][KPAD]
    unsigned short* w1eT = w0eT + 64 * KPAD;                // [128][64]
    unsigned short* cw0T = w1eT + 8192;                     // [64][128]

    const int eblocks32 = (E + TM - 1) / TM;
    const int eblocksS  = (E + TS - 1) / TS;

    wprep_k<<<(143360 + 255) / 256, 256, 0, stream>>>(mew0, mew1, mnw0, eew0, eew1, cw0,
                                                      w0T, w1T, wmT, w0eT, w1eT, cw0T);
    node_embed_k<<<N, 128, 0, stream>>>(x, new0, neb0, new1, neb1, nf0_bf, nf_bf);
    edge_embed_k<<<eblocks32, 256, 0, stream>>>(ea, w0eT, eeb0, w1eT, eeb1,
                                                ef0_bf, ef_bf, E);

    const int n4 = (N * ND) / 4;
    const int zgrid = (n4 + 255) / 256;
    zero_k<<<zgrid, 256, 0, stream>>>(nfn, n4);

    for (int s = 0; s < 4; s++) {
        edge_step_k<<<eblocksS, 256, 0, stream>>>(srcj, tgti, nf0_bf, nf_bf,
                                                  ef0_bf, ef_bf, nfn,
                                                  w0T, meb0, w1T, meb1, wmT, mnb0, E);
        f2bfz_k<<<zgrid, 256, 0, stream>>>(nfn, nf_bf, n4);
    }

    classify_k<<<eblocks32, 256, 0, stream>>>(ef_bf, cw0T, cb0, cw1, cb1, cw2, cb2,
                                              (float*)d_out, E);
}

// Round 10
// 826.315 us; speedup vs baseline: 1.6221x; 1.1838x over previous
//
#include <hip/hip_runtime.h>
#include <hip/hip_bf16.h>

#define ND 128
#define ED 128
#define NIN 128
#define EIN 291
#define KPAD 320   // EIN padded to multiple of 32
#define HH 64
#define TM 32      // edges/nodes per block in embed/classify MFMA kernels
#define TS 64      // edges per block in edge_step

typedef __attribute__((ext_vector_type(8))) short short8;
typedef __attribute__((ext_vector_type(4))) float float4_;

__device__ __forceinline__ unsigned short f2bf(float f)
{
    union { float f; unsigned u; } v; v.f = f;
    unsigned u = v.u;
    unsigned r = (u + 0x7FFFu + ((u >> 16) & 1u)) >> 16;  // RNE
    return (unsigned short)r;
}
__device__ __forceinline__ float bf2f(unsigned short s)
{
    union { unsigned u; float f; } v; v.u = ((unsigned)s) << 16;
    return v.f;
}

// Zero a float buffer.
__global__ __launch_bounds__(256) void zero_k(float* __restrict__ p, int n4)
{
    int idx = blockIdx.x * 256 + threadIdx.x;
    if (idx < n4) ((float4*)p)[idx] = make_float4(0.f, 0.f, 0.f, 0.f);
}

// Fused: convert fp32 accumulator -> bf16 activations, then zero the accumulator.
__global__ __launch_bounds__(256) void f2bfz_k(float* __restrict__ src,
                                               unsigned short* __restrict__ dst, int n4)
{
    int idx = blockIdx.x * 256 + threadIdx.x;
    if (idx < n4) {
        float4 v = ((const float4*)src)[idx];
        unsigned lo = (unsigned)f2bf(v.x) | ((unsigned)f2bf(v.y) << 16);
        unsigned hi = (unsigned)f2bf(v.z) | ((unsigned)f2bf(v.w) << 16);
        ((uint2*)dst)[idx] = make_uint2(lo, hi);
        ((float4*)src)[idx] = make_float4(0.f, 0.f, 0.f, 0.f);
    }
}

// One-time weight prep: transpose + fp32->bf16 (+ zero-pad K for edge-embed L1).
__global__ __launch_bounds__(256) void wprep_k(
    const float* __restrict__ mew0, const float* __restrict__ mew1, const float* __restrict__ mnw0,
    const float* __restrict__ eew0, const float* __restrict__ eew1, const float* __restrict__ cw0,
    const float* __restrict__ new0, const float* __restrict__ new1,
    unsigned short* __restrict__ w0T, unsigned short* __restrict__ w1T,
    unsigned short* __restrict__ wmT, unsigned short* __restrict__ w0eT,
    unsigned short* __restrict__ w1eT, unsigned short* __restrict__ cw0T,
    unsigned short* __restrict__ w0nT, unsigned short* __restrict__ w1nT)
{
    int idx = blockIdx.x * 256 + threadIdx.x;
    if (idx < 49152) {
        int c = idx / 768, k = idx % 768;
        w0T[idx] = f2bf(mew0[k * 64 + c]);
    } else if (idx < 57344) {
        int j = idx - 49152; int c = j / 64, k = j % 64;
        w1T[j] = f2bf(mew1[k * 128 + c]);
    } else if (idx < 106496) {
        int j = idx - 57344; int c = j / 384, k = j % 384;
        wmT[j] = f2bf(mnw0[k * 128 + c]);
    } else if (idx < 126976) {
        int j = idx - 106496; int c = j / KPAD, k = j % KPAD;
        w0eT[j] = (k < EIN) ? f2bf(eew0[k * 64 + c]) : (unsigned short)0;
    } else if (idx < 135168) {
        int j = idx - 126976; int c = j / 64, k = j % 64;
        w1eT[j] = f2bf(eew1[k * 128 + c]);
    } else if (idx < 143360) {
        int j = idx - 135168; int c = j / 128, k = j % 128;
        cw0T[j] = f2bf(cw0[k * 64 + c]);
    } else if (idx < 159744) {
        int j = idx - 143360; int c = j / 128, k = j % 128;
        w0nT[j] = f2bf(new0[k * 128 + c]);
    } else if (idx < 176128) {
        int j = idx - 159744; int c = j / 128, k = j % 128;
        w1nT[j] = f2bf(new1[k * 128 + c]);
    }
}

// MFMA node embed: 32 nodes/block. K=128 both layers. Weights full-staged in LDS.
__global__ __launch_bounds__(256) void node_embed_k(
    const float* __restrict__ x,
    const unsigned short* __restrict__ w0nT, const float* __restrict__ b0,
    const unsigned short* __restrict__ w1nT, const float* __restrict__ b1,
    unsigned short* __restrict__ nf0_bf, unsigned short* __restrict__ nf_bf, int N)
{
    const int t = threadIdx.x;
    const int n0 = blockIdx.x * TM;
    __shared__ unsigned short wreg[128 * 136];   // 34.8 KB staging (both layers)
    __shared__ unsigned short xin[TM][136];
    __shared__ unsigned short h_bf[TM][136];

    // stage x rows -> bf16 LDS (parallel, coalesced float4)
#pragma unroll
    for (int it = 0; it < 4; it++) {
        int idx = it * 256 + t;              // 1024 = 32 rows x 32 groups
        int r = idx >> 5, c4 = idx & 31;
        int node = n0 + r; if (node >= N) node = N - 1;
        float4 v = *(const float4*)(x + (size_t)node * NIN + c4 * 4);
        unsigned lo = (unsigned)f2bf(v.x) | ((unsigned)f2bf(v.y) << 16);
        unsigned hi = (unsigned)f2bf(v.z) | ((unsigned)f2bf(v.w) << 16);
        *(uint2*)&xin[r][c4 * 4] = make_uint2(lo, hi);
    }
    // stage w0nT: 128 cols x 128 k -> pitch 136
#pragma unroll
    for (int it = 0; it < 9; it++) {
        int idx = it * 256 + t;
        if (idx < 2048) {
            int c = idx >> 4, k8 = idx & 15;
            *(short8*)&wreg[c * 136 + k8 * 8] = *(const short8*)&w0nT[c * 128 + k8 * 8];
        }
    }
    __syncthreads();

    const int w = t >> 6, lane = t & 63, quad = lane >> 4, n16 = lane & 15;
    const int m = w & 1, nh = w >> 1;

    // L1: K=128, N=128; wave: M-tile m, N-half nh (4 tiles)
    {
        float4_ acc[4];
#pragma unroll
        for (int q = 0; q < 4; q++) acc[q] = (float4_){0.f, 0.f, 0.f, 0.f};
#pragma unroll
        for (int kc = 0; kc < 4; kc++) {
            short8 a = *(const short8*)&xin[m * 16 + n16][kc * 32 + quad * 8];
#pragma unroll
            for (int tt = 0; tt < 4; tt++) {
                short8 b = *(const short8*)&wreg[(nh * 64 + tt * 16 + n16) * 136 + kc * 32 + quad * 8];
                acc[tt] = __builtin_amdgcn_mfma_f32_16x16x32_bf16(a, b, acc[tt], 0, 0, 0);
            }
        }
#pragma unroll
        for (int tt = 0; tt < 4; tt++) {
            int c = nh * 64 + tt * 16 + n16;
            float bias = b0[c];
#pragma unroll
            for (int r4 = 0; r4 < 4; r4++)
                h_bf[m * 16 + quad * 4 + r4][c] = f2bf(fmaxf(acc[tt][r4] + bias, 0.f));
        }
    }
    __syncthreads();
    // restage w1nT
#pragma unroll
    for (int it = 0; it < 9; it++) {
        int idx = it * 256 + t;
        if (idx < 2048) {
            int c = idx >> 4, k8 = idx & 15;
            *(short8*)&wreg[c * 136 + k8 * 8] = *(const short8*)&w1nT[c * 128 + k8 * 8];
        }
    }
    __syncthreads();
    // L2: K=128, N=128 (no ReLU)
    {
        float4_ acc[4];
#pragma unroll
        for (int q = 0; q < 4; q++) acc[q] = (float4_){0.f, 0.f, 0.f, 0.f};
#pragma unroll
        for (int kc = 0; kc < 4; kc++) {
            short8 a = *(const short8*)&h_bf[m * 16 + n16][kc * 32 + quad * 8];
#pragma unroll
            for (int tt = 0; tt < 4; tt++) {
                short8 b = *(const short8*)&wreg[(nh * 64 + tt * 16 + n16) * 136 + kc * 32 + quad * 8];
                acc[tt] = __builtin_amdgcn_mfma_f32_16x16x32_bf16(a, b, acc[tt], 0, 0, 0);
            }
        }
#pragma unroll
        for (int tt = 0; tt < 4; tt++) {
            int c = nh * 64 + tt * 16 + n16;
            float bias = b1[c];
#pragma unroll
            for (int r4 = 0; r4 < 4; r4++) {
                int row = m * 16 + quad * 4 + r4;
                int node = n0 + row;
                if (node < N) {
                    unsigned short v = f2bf(acc[tt][r4] + bias);
                    nf0_bf[(size_t)node * ND + c] = v;
                    nf_bf[(size_t)node * ND + c] = v;
                }
            }
        }
    }
}

// MFMA edge embed: 32 edges/block. ea in LDS (bf16), weights LDS-staged
// (w0e in two K=160 halves through a reused region, then w1e).
__global__ __launch_bounds__(256) void edge_embed_k(
    const float* __restrict__ ea,
    const unsigned short* __restrict__ w0eT, const float* __restrict__ b0,
    const unsigned short* __restrict__ w1eT, const float* __restrict__ b1,
    unsigned short* __restrict__ ef0_bf, unsigned short* __restrict__ ef_bf, int E)
{
    const int t = threadIdx.x;
    const int e0 = blockIdx.x * TM;
    __shared__ unsigned short wreg[64 * 168];       // 21.5 KB region (w0e half / w1e)
    __shared__ unsigned short ea_bf[TM][KPAD + 8];  // 21 KB
    __shared__ unsigned short h_bf[TM][72];

    // stage ea -> bf16 LDS, parallel over rows x col-groups
#pragma unroll
    for (int it = 0; it < 10; it++) {
        int idx = it * 256 + t;                 // 2560 = 32 rows x 80 groups
        int r = idx / 80, c4 = idx % 80;
        int e = e0 + r; if (e >= E) e = E - 1;
        const float* src = ea + (size_t)e * EIN + c4 * 4;
        int base = c4 * 4;
        float v0 = (base + 0 < EIN) ? src[0] : 0.f;
        float v1 = (base + 1 < EIN) ? src[1] : 0.f;
        float v2 = (base + 2 < EIN) ? src[2] : 0.f;
        float v3 = (base + 3 < EIN) ? src[3] : 0.f;
        unsigned lo = (unsigned)f2bf(v0) | ((unsigned)f2bf(v1) << 16);
        unsigned hi = (unsigned)f2bf(v2) | ((unsigned)f2bf(v3) << 16);
        *(uint2*)&ea_bf[r][base] = make_uint2(lo, hi);
    }

    const int w = t >> 6, lane = t & 63, quad = lane >> 4, n16 = lane & 15;
    const int m = w & 1, nh = w >> 1;

    // L1: K=320 in two staged halves; wave: M-tile m, 2 N-tiles at nh*32
    float4_ accL[2];
    accL[0] = (float4_){0.f, 0.f, 0.f, 0.f}; accL[1] = accL[0];
#pragma unroll
    for (int hf = 0; hf < 2; hf++) {
        // stage w0e half: 64 cols x 160 shorts -> pitch 168
#pragma unroll
        for (int it = 0; it < 5; it++) {
            int idx = it * 256 + t;             // 1280 short8
            int c = idx / 20, k8 = idx % 20;
            *(short8*)&wreg[c * 168 + k8 * 8] =
                *(const short8*)&w0eT[c * KPAD + hf * 160 + k8 * 8];
        }
        __syncthreads();
#pragma unroll
        for (int kc = 0; kc < 5; kc++) {
            short8 a = *(const short8*)&ea_bf[m * 16 + n16][hf * 160 + kc * 32 + quad * 8];
#pragma unroll
            for (int tt = 0; tt < 2; tt++) {
                short8 b = *(const short8*)&wreg[(nh * 32 + tt * 16 + n16) * 168 + kc * 32 + quad * 8];
                accL[tt] = __builtin_amdgcn_mfma_f32_16x16x32_bf16(a, b, accL[tt], 0, 0, 0);
            }
        }
        __syncthreads();
    }
#pragma unroll
    for (int tt = 0; tt < 2; tt++) {
        int c = nh * 32 + tt * 16 + n16;
        float bias = b0[c];
#pragma unroll
        for (int r4 = 0; r4 < 4; r4++)
            h_bf[m * 16 + quad * 4 + r4][c] = f2bf(fmaxf(accL[tt][r4] + bias, 0.f));
    }
    // stage w1e: 128 cols x 64 shorts -> pitch 72
#pragma unroll
    for (int it = 0; it < 5; it++) {
        int idx = it * 256 + t;
        if (idx < 1152) {
            int c = idx / 9, k8 = idx % 9;     // 9 groups? no: 64 shorts = 8 short8
        }
    }
    // (correct staging below: 128 cols x 8 short8 = 1024)
#pragma unroll
    for (int it = 0; it < 4; it++) {
        int idx = it * 256 + t;                 // 1024
        int c = idx >> 3, k8 = idx & 7;
        *(short8*)&wreg[c * 72 + k8 * 8] = *(const short8*)&w1eT[c * 64 + k8 * 8];
    }
    __syncthreads();
    // L2: K=64, N=128 (no ReLU)
    {
        float4_ acc[4];
#pragma unroll
        for (int q = 0; q < 4; q++) acc[q] = (float4_){0.f, 0.f, 0.f, 0.f};
#pragma unroll
        for (int kc = 0; kc < 2; kc++) {
            short8 a = *(const short8*)&h_bf[m * 16 + n16][kc * 32 + quad * 8];
#pragma unroll
            for (int tt = 0; tt < 4; tt++) {
                short8 b = *(const short8*)&wreg[(nh * 64 + tt * 16 + n16) * 72 + kc * 32 + quad * 8];
                acc[tt] = __builtin_amdgcn_mfma_f32_16x16x32_bf16(a, b, acc[tt], 0, 0, 0);
            }
        }
#pragma unroll
        for (int tt = 0; tt < 4; tt++) {
            int c = nh * 64 + tt * 16 + n16;
            float bias = b1[c];
#pragma unroll
            for (int r4 = 0; r4 < 4; r4++) {
                int row = m * 16 + quad * 4 + r4;
                int e = e0 + row;
                if (e < E) {
                    unsigned short v = f2bf(acc[tt][r4] + bias);
                    ef0_bf[(size_t)e * ED + c] = v;
                    ef_bf[(size_t)e * ED + c] = v;
                }
            }
        }
    }
}

// MFMA MPN step: 64 edges/block, 4 waves; wave = one 16-edge M-tile, full N.
// Weights staged through a 26.6KB LDS region in K-quarters. A direct global.
__global__ __launch_bounds__(256, 2) void edge_step_k(
    const int* __restrict__ srcj, const int* __restrict__ tgti,
    const unsigned short* __restrict__ nf0_bf, const unsigned short* __restrict__ nf_bf,
    const unsigned short* __restrict__ ef0_bf, unsigned short* __restrict__ ef_bf,
    float* __restrict__ nfn,
    const unsigned short* __restrict__ w0T, const float* __restrict__ meb0,
    const unsigned short* __restrict__ w1T, const float* __restrict__ meb1,
    const unsigned short* __restrict__ wmT, const float* __restrict__ mnb0, int E)
{
    const int t = threadIdx.x;
    const int e0 = blockIdx.x * TS;
    __shared__ unsigned short wreg[13312];          // 26.6 KB (w0 qtr 12800 / w1 9216 / wm qtr 13312)
    __shared__ unsigned short h_bf[TS][72];
    __shared__ unsigned short efn_bf[TS][136];
    __shared__ int sidx[TS];

    if (t < TS) { int e = e0 + t; if (e >= E) e = E - 1; sidx[t] = tgti[e]; }

    const int w = t >> 6, lane = t & 63, quad = lane >> 4, n16 = lane & 15;
    const int erow = w * 16 + n16;
    int ec = e0 + erow; if (ec >= E) ec = E - 1;
    const int ti = tgti[ec], sj = srcj[ec];

    // preload 24 A-fragments
    short8 areg[24];
    {
        const unsigned short* pAs[6] = {
            nf0_bf + (size_t)ti * ND + quad * 8,
            nf_bf  + (size_t)ti * ND + quad * 8,
            nf0_bf + (size_t)sj * ND + quad * 8,
            nf_bf  + (size_t)sj * ND + quad * 8,
            ef0_bf + (size_t)ec * ED + quad * 8,
            ef_bf  + (size_t)ec * ED + quad * 8 };
#pragma unroll
        for (int f = 0; f < 24; f++)
            areg[f] = *(const short8*)(pAs[f >> 2] + (f & 3) * 32);
    }

    // ---- L1: K=768 in four staged quarters; wave: 16 edges x full N=64 ----
    float4_ accL[4];
#pragma unroll
    for (int q = 0; q < 4; q++) accL[q] = (float4_){0.f, 0.f, 0.f, 0.f};
#pragma unroll
    for (int hf = 0; hf < 4; hf++) {
        // stage w0 quarter: 64 cols x 192 shorts -> pitch 200
#pragma unroll
        for (int it = 0; it < 6; it++) {
            int idx = it * 256 + t;             // 1536 short8
            int c = idx / 24, k8 = idx % 24;
            *(short8*)&wreg[c * 200 + k8 * 8] =
                *(const short8*)&w0T[c * 768 + hf * 192 + k8 * 8];
        }
        __syncthreads();
#pragma unroll
        for (int kc = 0; kc < 6; kc++) {
#pragma unroll
            for (int tt = 0; tt < 4; tt++) {
                short8 b = *(const short8*)&wreg[(tt * 16 + n16) * 200 + kc * 32 + quad * 8];
                accL[tt] = __builtin_amdgcn_mfma_f32_16x16x32_bf16(areg[hf * 6 + kc], b, accL[tt], 0, 0, 0);
            }
        }
        __syncthreads();
    }
#pragma unroll
    for (int tt = 0; tt < 4; tt++) {
        int c = tt * 16 + n16;
        float bias = meb0[c];
#pragma unroll
        for (int r4 = 0; r4 < 4; r4++)
            h_bf[w * 16 + quad * 4 + r4][c] = f2bf(fmaxf(accL[tt][r4] + bias, 0.f));
    }

    // ---- stage w1 (128x64 -> pitch 72), L2: K=64, full N=128 ----
#pragma unroll
    for (int it = 0; it < 4; it++) {
        int idx = it * 256 + t;                 // 1024 short8
        int c = idx >> 3, k8 = idx & 7;
        *(short8*)&wreg[c * 72 + k8 * 8] = *(const short8*)&w1T[c * 64 + k8 * 8];
    }
    __syncthreads();
    {
        float4_ acc[8];
#pragma unroll
        for (int q = 0; q < 8; q++) acc[q] = (float4_){0.f, 0.f, 0.f, 0.f};
#pragma unroll
        for (int kc = 0; kc < 2; kc++) {
            short8 a = *(const short8*)&h_bf[w * 16 + n16][kc * 32 + quad * 8];
#pragma unroll
            for (int tt = 0; tt < 8; tt++) {
                short8 b = *(const short8*)&wreg[(tt * 16 + n16) * 72 + kc * 32 + quad * 8];
                acc[tt] = __builtin_amdgcn_mfma_f32_16x16x32_bf16(a, b, acc[tt], 0, 0, 0);
            }
        }
#pragma unroll
        for (int tt = 0; tt < 8; tt++) {
            int c = tt * 16 + n16;
            float bias = meb1[c];
#pragma unroll
            for (int r4 = 0; r4 < 4; r4++) {
                int row = w * 16 + quad * 4 + r4;
                unsigned short v = f2bf(fmaxf(acc[tt][r4] + bias, 0.f));
                efn_bf[row][c] = v;
                int e = e0 + row;
                if (e < E) ef_bf[(size_t)e * ED + c] = v;
            }
        }
    }
    __syncthreads();

    // ---- MSG: K=384 in four staged quarters (wm 128 x 96 -> pitch 104) ----
    float4_ accM[8];
#pragma unroll
    for (int q = 0; q < 8; q++) accM[q] = (float4_){0.f, 0.f, 0.f, 0.f};
#pragma unroll
    for (int hf = 0; hf < 4; hf++) {
#pragma unroll
        for (int it = 0; it < 6; it++) {
            int idx = it * 256 + t;             // 1536 short8
            int c = idx / 12, k8 = idx % 12;
            *(short8*)&wreg[c * 104 + k8 * 8] =
                *(const short8*)&wmT[c * 384 + hf * 96 + k8 * 8];
        }
        __syncthreads();
#pragma unroll
        for (int kc = 0; kc < 3; kc++) {
            int kk = hf * 3 + kc;
            short8 a;
            if (kk < 8) a = areg[kk];
            else        a = *(const short8*)&efn_bf[erow][(kk - 8) * 32 + quad * 8];
#pragma unroll
            for (int tt = 0; tt < 8; tt++) {
                short8 b = *(const short8*)&wreg[(tt * 16 + n16) * 104 + kc * 32 + quad * 8];
                accM[tt] = __builtin_amdgcn_mfma_f32_16x16x32_bf16(a, b, accM[tt], 0, 0, 0);
            }
        }
        __syncthreads();
    }
#pragma unroll
    for (int tt = 0; tt < 8; tt++) {
        int c = tt * 16 + n16;
        float bias = mnb0[c];
#pragma unroll
        for (int r4 = 0; r4 < 4; r4++) {
            int row = w * 16 + quad * 4 + r4;
            int e = e0 + row;
            if (e < E)
                atomicAdd(&nfn[(size_t)sidx[row] * ND + c],
                          fmaxf(accM[tt][r4] + bias, 0.f));
        }
    }
}

// classify: L1 (128->64, ReLU) via MFMA with direct-global A; L2/L3 scalar fp32.
__global__ __launch_bounds__(256) void classify_k(
    const unsigned short* __restrict__ ef_bf,
    const unsigned short* __restrict__ cw0T, const float* __restrict__ cb0,
    const float* __restrict__ cw1, const float* __restrict__ cb1,
    const float* __restrict__ cw2, const float* __restrict__ cb2,
    float* __restrict__ out, int E)
{
    const int t = threadIdx.x;
    const int e0 = blockIdx.x * TM;
    __shared__ unsigned short h0_bf[TM][72];
    __shared__ float h1[TM][33];

    const int w = t >> 6, lane = t & 63, quad = lane >> 4, n16 = lane & 15;
    const int m = w & 1;
    const int erow = m * 16 + n16;
    int ec = e0 + erow; if (ec >= E) ec = E - 1;
    const unsigned short* pa = ef_bf + (size_t)ec * ED + quad * 8;

    {
        const int cb = (w >> 1) * 32;
        float4_ acc0 = {0.f, 0.f, 0.f, 0.f}, acc1 = acc0;
        const unsigned short* b0p = cw0T + (size_t)(cb + n16) * 128 + quad * 8;
        const unsigned short* b1p = b0p + (size_t)16 * 128;
#pragma unroll
        for (int kc = 0; kc < 4; kc++) {
            short8 a  = *(const short8*)(pa + kc * 32);
            short8 bb0 = *(const short8*)(b0p + kc * 32);
            short8 bb1 = *(const short8*)(b1p + kc * 32);
            acc0 = __builtin_amdgcn_mfma_f32_16x16x32_bf16(a, bb0, acc0, 0, 0, 0);
            acc1 = __builtin_amdgcn_mfma_f32_16x16x32_bf16(a, bb1, acc1, 0, 0, 0);
        }
#pragma unroll
        for (int t2 = 0; t2 < 2; t2++) {
            int c = cb + t2 * 16 + n16;
            float bias = cb0[c];
            float4_ ac = t2 ? acc1 : acc0;
#pragma unroll
            for (int r4 = 0; r4 < 4; r4++)
                h0_bf[m * 16 + quad * 4 + r4][c] = f2bf(fmaxf(ac[r4] + bias, 0.f));
        }
    }
    __syncthreads();

    {
        int c = t & 31;
        int rbase = (t >> 5) * 4;
#pragma unroll
        for (int q = 0; q < 4; q++) {
            int r = rbase + q;
            float acc = cb1[c];
#pragma unroll 8
            for (int k = 0; k < 64; k++) acc += bf2f(h0_bf[r][k]) * cw1[k * 32 + c];
            h1[r][c] = fmaxf(acc, 0.f);
        }
    }
    __syncthreads();

    if (t < TM) {
        int e = e0 + t;
        if (e < E) {
            float a = cb2[0];
#pragma unroll
            for (int k = 0; k < 32; k++) a += h1[t][k] * cw2[k];
            out[e] = a;
        }
    }
}

extern "C" void kernel_launch(void* const* d_in, const int* in_sizes, int n_in,
                              void* d_out, int out_size, void* d_ws, size_t ws_size,
                              hipStream_t stream)
{
    const float* x    = (const float*)d_in[0];
    const float* ea   = (const float*)d_in[1];
    const int*   eidx = (const int*)d_in[2];
    const float* new0 = (const float*)d_in[3];  const float* neb0 = (const float*)d_in[4];
    const float* new1 = (const float*)d_in[5];  const float* neb1 = (const float*)d_in[6];
    const float* eew0 = (const float*)d_in[7];  const float* eeb0 = (const float*)d_in[8];
    const float* eew1 = (const float*)d_in[9];  const float* eeb1 = (const float*)d_in[10];
    const float* mew0 = (const float*)d_in[11]; const float* meb0 = (const float*)d_in[12];
    const float* mew1 = (const float*)d_in[13]; const float* meb1 = (const float*)d_in[14];
    const float* mnw0 = (const float*)d_in[15]; const float* mnb0 = (const float*)d_in[16];
    const float* cw0  = (const float*)d_in[17]; const float* cb0  = (const float*)d_in[18];
    const float* cw1  = (const float*)d_in[19]; const float* cb1  = (const float*)d_in[20];
    const float* cw2  = (const float*)d_in[21]; const float* cb2  = (const float*)d_in[22];

    const int N = in_sizes[0] / NIN;   // 20000
    const int E = in_sizes[2] / 2;     // 100000
    const int* srcj = eidx;            // edge_index[0] = j (source)
    const int* tgti = eidx + E;        // edge_index[1] = i (target)

    char* wsb = (char*)d_ws;
    float* nfn = (float*)wsb;                               // N*ND fp32 accum
    unsigned short* nf0_bf = (unsigned short*)(nfn + (size_t)N * ND);
    unsigned short* nf_bf  = nf0_bf + (size_t)N * ND;
    unsigned short* ef0_bf = nf_bf + (size_t)N * ND;
    unsigned short* ef_bf  = ef0_bf + (size_t)E * ED;
    unsigned short* w0T  = ef_bf + (size_t)E * ED;          // [64][768]
    unsigned short* w1T  = w0T + 49152;                     // [128][64]
    unsigned short* wmT  = w1T + 8192;                      // [128][384]
    unsigned short* w0eT = wmT + 49152;                     // [64][KPAD]
    unsigned short* w1eT = w0eT + 64 * KPAD;                // [128][64]
    unsigned short* cw0T = w1eT + 8192;                     // [64][128]
    unsigned short* w0nT = cw0T + 8192;                     // [128][128]
    unsigned short* w1nT = w0nT + 16384;                    // [128][128]

    const int eblocks32 = (E + TM - 1) / TM;
    const int eblocksS  = (E + TS - 1) / TS;
    const int nblocks32 = (N + TM - 1) / TM;

    wprep_k<<<(176128 + 255) / 256, 256, 0, stream>>>(mew0, mew1, mnw0, eew0, eew1, cw0,
                                                      new0, new1,
                                                      w0T, w1T, wmT, w0eT, w1eT, cw0T,
                                                      w0nT, w1nT);
    node_embed_k<<<nblocks32, 256, 0, stream>>>(x, w0nT, neb0, w1nT, neb1,
                                                nf0_bf, nf_bf, N);
    edge_embed_k<<<eblocks32, 256, 0, stream>>>(ea, w0eT, eeb0, w1eT, eeb1,
                                                ef0_bf, ef_bf, E);

    const int n4 = (N * ND) / 4;
    const int zgrid = (n4 + 255) / 256;
    zero_k<<<zgrid, 256, 0, stream>>>(nfn, n4);

    for (int s = 0; s < 4; s++) {
        edge_step_k<<<eblocksS, 256, 0, stream>>>(srcj, tgti, nf0_bf, nf_bf,
                                                  ef0_bf, ef_bf, nfn,
                                                  w0T, meb0, w1T, meb1, wmT, mnb0, E);
        f2bfz_k<<<zgrid, 256, 0, stream>>>(nfn, nf_bf, n4);
    }

    classify_k<<<eblocks32, 256, 0, stream>>>(ef_bf, cw0T, cb0, cw1, cb1, cw2, cb2,
                                              (float*)d_out, E);
}

// Round 11
// 812.837 us; speedup vs baseline: 1.6490x; 1.0166x over previous
//
#include <hip/hip_runtime.h>
#include <hip/hip_bf16.h>

#define ND 128
#define ED 128
#define NIN 128
#define EIN 291
#define KPAD 320   // EIN padded to multiple of 32
#define HH 64
#define TM 32      // edges/nodes per block in embed/classify MFMA kernels
#define TS 64      // edges per block in edge_step

typedef __attribute__((ext_vector_type(8))) short short8;
typedef __attribute__((ext_vector_type(4))) float float4_;

__device__ __forceinline__ unsigned short f2bf(float f)
{
    union { float f; unsigned u; } v; v.f = f;
    unsigned u = v.u;
    unsigned r = (u + 0x7FFFu + ((u >> 16) & 1u)) >> 16;  // RNE
    return (unsigned short)r;
}
__device__ __forceinline__ float bf2f(unsigned short s)
{
    union { unsigned u; float f; } v; v.u = ((unsigned)s) << 16;
    return v.f;
}

// Stage T N-tiles x KC k-chunks of B (layout [col][K], bf16) into LDS in MFMA
// FRAGMENT ORDER: fragment f=tt*KC+kc occupies 64 consecutive short8 slots
// (one per lane). Both the LDS writes here and the ds_read_b128 in the MFMA
// loop are lane-contiguous -> zero bank conflicts.
template<int T, int KC, int K>
__device__ __forceinline__ void stage_frags(const unsigned short* __restrict__ src,
                                            unsigned short* __restrict__ wreg,
                                            int t, int k0)
{
    constexpr int TOT = T * KC * 64;     // short8 count (TOT/256 iters)
#pragma unroll
    for (int it = 0; it < TOT / 256; it++) {
        int idx = it * 256 + t;
        int f = idx >> 6, l = idx & 63;
        int col = (f / KC) * 16 + (l & 15);
        int k = (f % KC) * 32 + ((l >> 4) * 8);
        *(short8*)&wreg[idx * 8] = *(const short8*)&src[(size_t)col * K + k0 + k];
    }
}
#define FRAG(wreg, f, lane) (*(const short8*)&(wreg)[(((f) << 6) + (lane)) * 8])

// Zero a float buffer.
__global__ __launch_bounds__(256) void zero_k(float* __restrict__ p, int n4)
{
    int idx = blockIdx.x * 256 + threadIdx.x;
    if (idx < n4) ((float4*)p)[idx] = make_float4(0.f, 0.f, 0.f, 0.f);
}

// Fused: convert fp32 accumulator -> bf16 activations, then zero the accumulator.
__global__ __launch_bounds__(256) void f2bfz_k(float* __restrict__ src,
                                               unsigned short* __restrict__ dst, int n4)
{
    int idx = blockIdx.x * 256 + threadIdx.x;
    if (idx < n4) {
        float4 v = ((const float4*)src)[idx];
        unsigned lo = (unsigned)f2bf(v.x) | ((unsigned)f2bf(v.y) << 16);
        unsigned hi = (unsigned)f2bf(v.z) | ((unsigned)f2bf(v.w) << 16);
        ((uint2*)dst)[idx] = make_uint2(lo, hi);
        ((float4*)src)[idx] = make_float4(0.f, 0.f, 0.f, 0.f);
    }
}

// One-time weight prep: transpose + fp32->bf16 (+ zero-pad K for edge-embed L1).
__global__ __launch_bounds__(256) void wprep_k(
    const float* __restrict__ mew0, const float* __restrict__ mew1, const float* __restrict__ mnw0,
    const float* __restrict__ eew0, const float* __restrict__ eew1, const float* __restrict__ cw0,
    const float* __restrict__ new0, const float* __restrict__ new1,
    unsigned short* __restrict__ w0T, unsigned short* __restrict__ w1T,
    unsigned short* __restrict__ wmT, unsigned short* __restrict__ w0eT,
    unsigned short* __restrict__ w1eT, unsigned short* __restrict__ cw0T,
    unsigned short* __restrict__ w0nT, unsigned short* __restrict__ w1nT)
{
    int idx = blockIdx.x * 256 + threadIdx.x;
    if (idx < 49152) {
        int c = idx / 768, k = idx % 768;
        w0T[idx] = f2bf(mew0[k * 64 + c]);
    } else if (idx < 57344) {
        int j = idx - 49152; int c = j / 64, k = j % 64;
        w1T[j] = f2bf(mew1[k * 128 + c]);
    } else if (idx < 106496) {
        int j = idx - 57344; int c = j / 384, k = j % 384;
        wmT[j] = f2bf(mnw0[k * 128 + c]);
    } else if (idx < 126976) {
        int j = idx - 106496; int c = j / KPAD, k = j % KPAD;
        w0eT[j] = (k < EIN) ? f2bf(eew0[k * 64 + c]) : (unsigned short)0;
    } else if (idx < 135168) {
        int j = idx - 126976; int c = j / 64, k = j % 64;
        w1eT[j] = f2bf(eew1[k * 128 + c]);
    } else if (idx < 143360) {
        int j = idx - 135168; int c = j / 128, k = j % 128;
        cw0T[j] = f2bf(cw0[k * 64 + c]);
    } else if (idx < 159744) {
        int j = idx - 143360; int c = j / 128, k = j % 128;
        w0nT[j] = f2bf(new0[k * 128 + c]);
    } else if (idx < 176128) {
        int j = idx - 159744; int c = j / 128, k = j % 128;
        w1nT[j] = f2bf(new1[k * 128 + c]);
    }
}

// MFMA node embed: 32 nodes/block. K=128 both layers; weights staged in K-halves
// (fragment order). LDS ~33KB -> 4 blocks/CU.
__global__ __launch_bounds__(256) void node_embed_k(
    const float* __restrict__ x,
    const unsigned short* __restrict__ w0nT, const float* __restrict__ b0,
    const unsigned short* __restrict__ w1nT, const float* __restrict__ b1,
    unsigned short* __restrict__ nf0_bf, unsigned short* __restrict__ nf_bf, int N)
{
    const int t = threadIdx.x;
    const int n0 = blockIdx.x * TM;
    __shared__ unsigned short wreg[8192];        // 16.4 KB (one K-half, frag order)
    __shared__ unsigned short xin[TM][130];
    __shared__ unsigned short h_bf[TM][130];

#pragma unroll
    for (int it = 0; it < 4; it++) {
        int idx = it * 256 + t;              // 1024 = 32 rows x 32 groups
        int r = idx >> 5, c4 = idx & 31;
        int node = n0 + r; if (node >= N) node = N - 1;
        float4 v = *(const float4*)(x + (size_t)node * NIN + c4 * 4);
        unsigned lo = (unsigned)f2bf(v.x) | ((unsigned)f2bf(v.y) << 16);
        unsigned hi = (unsigned)f2bf(v.z) | ((unsigned)f2bf(v.w) << 16);
        *(uint2*)&xin[r][c4 * 4] = make_uint2(lo, hi);
    }

    const int w = t >> 6, lane = t & 63, quad = lane >> 4, n16 = lane & 15;
    const int m = w & 1, nh = w >> 1;

    // L1: K=128 in two halves; wave: M-tile m, N-tiles nh*4..+3 (T=8 staged)
    float4_ acc[4];
#pragma unroll
    for (int q = 0; q < 4; q++) acc[q] = (float4_){0.f, 0.f, 0.f, 0.f};
#pragma unroll
    for (int hf = 0; hf < 2; hf++) {
        stage_frags<8, 2, 128>(w0nT, wreg, t, hf * 64);
        __syncthreads();
#pragma unroll
        for (int kc = 0; kc < 2; kc++) {
            short8 a = *(const short8*)&xin[m * 16 + n16][hf * 64 + kc * 32 + quad * 8];
#pragma unroll
            for (int tt = 0; tt < 4; tt++) {
                short8 b = FRAG(wreg, (nh * 4 + tt) * 2 + kc, lane);
                acc[tt] = __builtin_amdgcn_mfma_f32_16x16x32_bf16(a, b, acc[tt], 0, 0, 0);
            }
        }
        __syncthreads();
    }
#pragma unroll
    for (int tt = 0; tt < 4; tt++) {
        int c = nh * 64 + tt * 16 + n16;
        float bias = b0[c];
#pragma unroll
        for (int r4 = 0; r4 < 4; r4++)
            h_bf[m * 16 + quad * 4 + r4][c] = f2bf(fmaxf(acc[tt][r4] + bias, 0.f));
    }
    __syncthreads();

    // L2: K=128 in two halves (no ReLU)
    float4_ acc2[4];
#pragma unroll
    for (int q = 0; q < 4; q++) acc2[q] = (float4_){0.f, 0.f, 0.f, 0.f};
#pragma unroll
    for (int hf = 0; hf < 2; hf++) {
        stage_frags<8, 2, 128>(w1nT, wreg, t, hf * 64);
        __syncthreads();
#pragma unroll
        for (int kc = 0; kc < 2; kc++) {
            short8 a = *(const short8*)&h_bf[m * 16 + n16][hf * 64 + kc * 32 + quad * 8];
#pragma unroll
            for (int tt = 0; tt < 4; tt++) {
                short8 b = FRAG(wreg, (nh * 4 + tt) * 2 + kc, lane);
                acc2[tt] = __builtin_amdgcn_mfma_f32_16x16x32_bf16(a, b, acc2[tt], 0, 0, 0);
            }
        }
        __syncthreads();
    }
#pragma unroll
    for (int tt = 0; tt < 4; tt++) {
        int c = nh * 64 + tt * 16 + n16;
        float bias = b1[c];
#pragma unroll
        for (int r4 = 0; r4 < 4; r4++) {
            int row = m * 16 + quad * 4 + r4;
            int node = n0 + row;
            if (node < N) {
                unsigned short v = f2bf(acc2[tt][r4] + bias);
                nf0_bf[(size_t)node * ND + c] = v;
                nf_bf[(size_t)node * ND + c] = v;
            }
        }
    }
}

// MFMA edge embed: 32 edges/block. ea bf16 in LDS; weights fragment-staged.
__global__ __launch_bounds__(256) void edge_embed_k(
    const float* __restrict__ ea,
    const unsigned short* __restrict__ w0eT, const float* __restrict__ b0,
    const unsigned short* __restrict__ w1eT, const float* __restrict__ b1,
    unsigned short* __restrict__ ef0_bf, unsigned short* __restrict__ ef_bf, int E)
{
    const int t = threadIdx.x;
    const int e0 = blockIdx.x * TM;
    __shared__ unsigned short wreg[10240];          // 20.5 KB (w0e half: 20 frags)
    __shared__ unsigned short ea_bf[TM][330];
    __shared__ unsigned short h_bf[TM][66];

#pragma unroll
    for (int it = 0; it < 10; it++) {
        int idx = it * 256 + t;                 // 2560 = 32 rows x 80 groups
        int r = idx / 80, c4 = idx % 80;
        int e = e0 + r; if (e >= E) e = E - 1;
        const float* src = ea + (size_t)e * EIN + c4 * 4;
        int base = c4 * 4;
        float v0 = (base + 0 < EIN) ? src[0] : 0.f;
        float v1 = (base + 1 < EIN) ? src[1] : 0.f;
        float v2 = (base + 2 < EIN) ? src[2] : 0.f;
        float v3 = (base + 3 < EIN) ? src[3] : 0.f;
        unsigned lo = (unsigned)f2bf(v0) | ((unsigned)f2bf(v1) << 16);
        unsigned hi = (unsigned)f2bf(v2) | ((unsigned)f2bf(v3) << 16);
        *(uint2*)&ea_bf[r][base] = make_uint2(lo, hi);
    }

    const int w = t >> 6, lane = t & 63, quad = lane >> 4, n16 = lane & 15;
    const int m = w & 1, nh = w >> 1;

    // L1: K=320 in two halves; wave: M-tile m, tiles nh*2..+1 (T=4 staged)
    float4_ accL[2];
    accL[0] = (float4_){0.f, 0.f, 0.f, 0.f}; accL[1] = accL[0];
#pragma unroll
    for (int hf = 0; hf < 2; hf++) {
        stage_frags<4, 5, KPAD>(w0eT, wreg, t, hf * 160);
        __syncthreads();
#pragma unroll
        for (int kc = 0; kc < 5; kc++) {
            short8 a = *(const short8*)&ea_bf[m * 16 + n16][hf * 160 + kc * 32 + quad * 8];
#pragma unroll
            for (int tt = 0; tt < 2; tt++) {
                short8 b = FRAG(wreg, (nh * 2 + tt) * 5 + kc, lane);
                accL[tt] = __builtin_amdgcn_mfma_f32_16x16x32_bf16(a, b, accL[tt], 0, 0, 0);
            }
        }
        __syncthreads();
    }
#pragma unroll
    for (int tt = 0; tt < 2; tt++) {
        int c = nh * 32 + tt * 16 + n16;
        float bias = b0[c];
#pragma unroll
        for (int r4 = 0; r4 < 4; r4++)
            h_bf[m * 16 + quad * 4 + r4][c] = f2bf(fmaxf(accL[tt][r4] + bias, 0.f));
    }
    __syncthreads();
    // L2: K=64 (T=8, KC=2, full stage), no ReLU
    stage_frags<8, 2, 64>(w1eT, wreg, t, 0);
    __syncthreads();
    {
        float4_ acc[4];
#pragma unroll
        for (int q = 0; q < 4; q++) acc[q] = (float4_){0.f, 0.f, 0.f, 0.f};
#pragma unroll
        for (int kc = 0; kc < 2; kc++) {
            short8 a = *(const short8*)&h_bf[m * 16 + n16][kc * 32 + quad * 8];
#pragma unroll
            for (int tt = 0; tt < 4; tt++) {
                short8 b = FRAG(wreg, (nh * 4 + tt) * 2 + kc, lane);
                acc[tt] = __builtin_amdgcn_mfma_f32_16x16x32_bf16(a, b, acc[tt], 0, 0, 0);
            }
        }
#pragma unroll
        for (int tt = 0; tt < 4; tt++) {
            int c = nh * 64 + tt * 16 + n16;
            float bias = b1[c];
#pragma unroll
            for (int r4 = 0; r4 < 4; r4++) {
                int row = m * 16 + quad * 4 + r4;
                int e = e0 + row;
                if (e < E) {
                    unsigned short v = f2bf(acc[tt][r4] + bias);
                    ef0_bf[(size_t)e * ED + c] = v;
                    ef_bf[(size_t)e * ED + c] = v;
                }
            }
        }
    }
}

// MFMA MPN step: 64 edges/block, 4 waves; wave = one 16-edge M-tile, full N.
// Weights fragment-staged in K-sixths (w0, wm) / full (w1) through a 16.4KB
// region -> conflict-free ds_read_b128; LDS ~41.7KB -> 3 blocks/CU.
__global__ __launch_bounds__(256, 3) void edge_step_k(
    const int* __restrict__ srcj, const int* __restrict__ tgti,
    const unsigned short* __restrict__ nf0_bf, const unsigned short* __restrict__ nf_bf,
    const unsigned short* __restrict__ ef0_bf, unsigned short* __restrict__ ef_bf,
    float* __restrict__ nfn,
    const unsigned short* __restrict__ w0T, const float* __restrict__ meb0,
    const unsigned short* __restrict__ w1T, const float* __restrict__ meb1,
    const unsigned short* __restrict__ wmT, const float* __restrict__ mnb0, int E)
{
    const int t = threadIdx.x;
    const int e0 = blockIdx.x * TS;
    __shared__ unsigned short wreg[8192];           // 16.4 KB fragment region
    __shared__ unsigned short h_bf[TS][66];
    __shared__ unsigned short efn_bf[TS][130];
    __shared__ int sidx[TS];

    if (t < TS) { int e = e0 + t; if (e >= E) e = E - 1; sidx[t] = tgti[e]; }

    const int w = t >> 6, lane = t & 63, quad = lane >> 4, n16 = lane & 15;
    const int erow = w * 16 + n16;
    int ec = e0 + erow; if (ec >= E) ec = E - 1;
    const int ti = tgti[ec], sj = srcj[ec];

    short8 areg[24];
    {
        const unsigned short* pAs[6] = {
            nf0_bf + (size_t)ti * ND + quad * 8,
            nf_bf  + (size_t)ti * ND + quad * 8,
            nf0_bf + (size_t)sj * ND + quad * 8,
            nf_bf  + (size_t)sj * ND + quad * 8,
            ef0_bf + (size_t)ec * ED + quad * 8,
            ef_bf  + (size_t)ec * ED + quad * 8 };
#pragma unroll
        for (int f = 0; f < 24; f++)
            areg[f] = *(const short8*)(pAs[f >> 2] + (f & 3) * 32);
    }

    // ---- L1: K=768 in six staged sixths (T=4, KC=4); full N=64 per wave ----
    float4_ accL[4];
#pragma unroll
    for (int q = 0; q < 4; q++) accL[q] = (float4_){0.f, 0.f, 0.f, 0.f};
#pragma unroll
    for (int hf = 0; hf < 6; hf++) {
        stage_frags<4, 4, 768>(w0T, wreg, t, hf * 128);
        __syncthreads();
#pragma unroll
        for (int kc = 0; kc < 4; kc++) {
#pragma unroll
            for (int tt = 0; tt < 4; tt++) {
                short8 b = FRAG(wreg, tt * 4 + kc, lane);
                accL[tt] = __builtin_amdgcn_mfma_f32_16x16x32_bf16(areg[hf * 4 + kc], b, accL[tt], 0, 0, 0);
            }
        }
        __syncthreads();
    }
#pragma unroll
    for (int tt = 0; tt < 4; tt++) {
        int c = tt * 16 + n16;
        float bias = meb0[c];
#pragma unroll
        for (int r4 = 0; r4 < 4; r4++)
            h_bf[w * 16 + quad * 4 + r4][c] = f2bf(fmaxf(accL[tt][r4] + bias, 0.f));
    }
    __syncthreads();

    // ---- L2: K=64 (T=8, KC=2 full stage); full N=128 ----
    stage_frags<8, 2, 64>(w1T, wreg, t, 0);
    __syncthreads();
    {
        float4_ acc[8];
#pragma unroll
        for (int q = 0; q < 8; q++) acc[q] = (float4_){0.f, 0.f, 0.f, 0.f};
#pragma unroll
        for (int kc = 0; kc < 2; kc++) {
            short8 a = *(const short8*)&h_bf[w * 16 + n16][kc * 32 + quad * 8];
#pragma unroll
            for (int tt = 0; tt < 8; tt++) {
                short8 b = FRAG(wreg, tt * 2 + kc, lane);
                acc[tt] = __builtin_amdgcn_mfma_f32_16x16x32_bf16(a, b, acc[tt], 0, 0, 0);
            }
        }
#pragma unroll
        for (int tt = 0; tt < 8; tt++) {
            int c = tt * 16 + n16;
            float bias = meb1[c];
#pragma unroll
            for (int r4 = 0; r4 < 4; r4++) {
                int row = w * 16 + quad * 4 + r4;
                unsigned short v = f2bf(fmaxf(acc[tt][r4] + bias, 0.f));
                efn_bf[row][c] = v;
                int e = e0 + row;
                if (e < E) ef_bf[(size_t)e * ED + c] = v;
            }
        }
    }
    __syncthreads();

    // ---- MSG: K=384 in six staged sixths (T=8, KC=2); atomic scatter ----
    float4_ accM[8];
#pragma unroll
    for (int q = 0; q < 8; q++) accM[q] = (float4_){0.f, 0.f, 0.f, 0.f};
#pragma unroll
    for (int hf = 0; hf < 6; hf++) {
        stage_frags<8, 2, 384>(wmT, wreg, t, hf * 64);
        __syncthreads();
#pragma unroll
        for (int kc = 0; kc < 2; kc++) {
            int kk = hf * 2 + kc;
            short8 a;
            if (kk < 8) a = areg[kk];
            else        a = *(const short8*)&efn_bf[erow][(kk - 8) * 32 + quad * 8];
#pragma unroll
            for (int tt = 0; tt < 8; tt++) {
                short8 b = FRAG(wreg, tt * 2 + kc, lane);
                accM[tt] = __builtin_amdgcn_mfma_f32_16x16x32_bf16(a, b, accM[tt], 0, 0, 0);
            }
        }
        __syncthreads();
    }
#pragma unroll
    for (int tt = 0; tt < 8; tt++) {
        int c = tt * 16 + n16;
        float bias = mnb0[c];
#pragma unroll
        for (int r4 = 0; r4 < 4; r4++) {
            int row = w * 16 + quad * 4 + r4;
            int e = e0 + row;
            if (e < E)
                atomicAdd(&nfn[(size_t)sidx[row] * ND + c],
                          fmaxf(accM[tt][r4] + bias, 0.f));
        }
    }
}

// classify: L1 (128->64, ReLU) via MFMA with direct-global A; L2/L3 scalar fp32.
__global__ __launch_bounds__(256) void classify_k(
    const unsigned short* __restrict__ ef_bf,
    const unsigned short* __restrict__ cw0T, const float* __restrict__ cb0,
    const float* __restrict__ cw1, const float* __restrict__ cb1,
    const float* __restrict__ cw2, const float* __restrict__ cb2,
    float* __restrict__ out, int E)
{
    const int t = threadIdx.x;
    const int e0 = blockIdx.x * TM;
    __shared__ unsigned short h0_bf[TM][66];
    __shared__ float h1[TM][33];

    const int w = t >> 6, lane = t & 63, quad = lane >> 4, n16 = lane & 15;
    const int m = w & 1;
    const int erow = m * 16 + n16;
    int ec = e0 + erow; if (ec >= E) ec = E - 1;
    const unsigned short* pa = ef_bf + (size_t)ec * ED + quad * 8;

    {
        const int cb = (w >> 1) * 32;
        float4_ acc0 = {0.f, 0.f, 0.f, 0.f}, acc1 = acc0;
        const unsigned short* b0p = cw0T + (size_t)(cb + n16) * 128 + quad * 8;
        const unsigned short* b1p = b0p + (size_t)16 * 128;
#pragma unroll
        for (int kc = 0; kc < 4; kc++) {
            short8 a  = *(const short8*)(pa + kc * 32);
            short8 bb0 = *(const short8*)(b0p + kc * 32);
            short8 bb1 = *(const short8*)(b1p + kc * 32);
            acc0 = __builtin_amdgcn_mfma_f32_16x16x32_bf16(a, bb0, acc0, 0, 0, 0);
            acc1 = __builtin_amdgcn_mfma_f32_16x16x32_bf16(a, bb1, acc1, 0, 0, 0);
        }
#pragma unroll
        for (int t2 = 0; t2 < 2; t2++) {
            int c = cb + t2 * 16 + n16;
            float bias = cb0[c];
            float4_ ac = t2 ? acc1 : acc0;
#pragma unroll
            for (int r4 = 0; r4 < 4; r4++)
                h0_bf[m * 16 + quad * 4 + r4][c] = f2bf(fmaxf(ac[r4] + bias, 0.f));
        }
    }
    __syncthreads();

    {
        int c = t & 31;
        int rbase = (t >> 5) * 4;
#pragma unroll
        for (int q = 0; q < 4; q++) {
            int r = rbase + q;
            float acc = cb1[c];
#pragma unroll 8
            for (int k = 0; k < 64; k++) acc += bf2f(h0_bf[r][k]) * cw1[k * 32 + c];
            h1[r][c] = fmaxf(acc, 0.f);
        }
    }
    __syncthreads();

    if (t < TM) {
        int e = e0 + t;
        if (e < E) {
            float a = cb2[0];
#pragma unroll
            for (int k = 0; k < 32; k++) a += h1[t][k] * cw2[k];
            out[e] = a;
        }
    }
}

extern "C" void kernel_launch(void* const* d_in, const int* in_sizes, int n_in,
                              void* d_out, int out_size, void* d_ws, size_t ws_size,
                              hipStream_t stream)
{
    const float* x    = (const float*)d_in[0];
    const float* ea   = (const float*)d_in[1];
    const int*   eidx = (const int*)d_in[2];
    const float* new0 = (const float*)d_in[3];  const float* neb0 = (const float*)d_in[4];
    const float* new1 = (const float*)d_in[5];  const float* neb1 = (const float*)d_in[6];
    const float* eew0 = (const float*)d_in[7];  const float* eeb0 = (const float*)d_in[8];
    const float* eew1 = (const float*)d_in[9];  const float* eeb1 = (const float*)d_in[10];
    const float* mew0 = (const float*)d_in[11]; const float* meb0 = (const float*)d_in[12];
    const float* mew1 = (const float*)d_in[13]; const float* meb1 = (const float*)d_in[14];
    const float* mnw0 = (const float*)d_in[15]; const float* mnb0 = (const float*)d_in[16];
    const float* cw0  = (const float*)d_in[17]; const float* cb0  = (const float*)d_in[18];
    const float* cw1  = (const float*)d_in[19]; const float* cb1  = (const float*)d_in[20];
    const float* cw2  = (const float*)d_in[21]; const float* cb2  = (const float*)d_in[22];

    const int N = in_sizes[0] / NIN;   // 20000
    const int E = in_sizes[2] / 2;     // 100000
    const int* srcj = eidx;            // edge_index[0] = j (source)
    const int* tgti = eidx + E;        // edge_index[1] = i (target)

    char* wsb = (char*)d_ws;
    float* nfn = (float*)wsb;                               // N*ND fp32 accum
    unsigned short* nf0_bf = (unsigned short*)(nfn + (size_t)N * ND);
    unsigned short* nf_bf  = nf0_bf + (size_t)N * ND;
    unsigned short* ef0_bf = nf_bf + (size_t)N * ND;
    unsigned short* ef_bf  = ef0_bf + (size_t)E * ED;
    unsigned short* w0T  = ef_bf + (size_t)E * ED;          // [64][768]
    unsigned short* w1T  = w0T + 49152;                     // [128][64]
    unsigned short* wmT  = w1T + 8192;                      // [128][384]
    unsigned short* w0eT = wmT + 49152;                     // [64][KPAD]
    unsigned short* w1eT = w0eT + 64 * KPAD;                // [128][64]
    unsigned short* cw0T = w1eT + 8192;                     // [64][128]
    unsigned short* w0nT = cw0T + 8192;                     // [128][128]
    unsigned short* w1nT = w0nT + 16384;                    // [128][128]

    const int eblocks32 = (E + TM - 1) / TM;
    const int eblocksS  = (E + TS - 1) / TS;
    const int nblocks32 = (N + TM - 1) / TM;

    wprep_k<<<(176128 + 255) / 256, 256, 0, stream>>>(mew0, mew1, mnw0, eew0, eew1, cw0,
                                                      new0, new1,
                                                      w0T, w1T, wmT, w0eT, w1eT, cw0T,
                                                      w0nT, w1nT);
    node_embed_k<<<nblocks32, 256, 0, stream>>>(x, w0nT, neb0, w1nT, neb1,
                                                nf0_bf, nf_bf, N);
    edge_embed_k<<<eblocks32, 256, 0, stream>>>(ea, w0eT, eeb0, w1eT, eeb1,
                                                ef0_bf, ef_bf, E);

    const int n4 = (N * ND) / 4;
    const int zgrid = (n4 + 255) / 256;
    zero_k<<<zgrid, 256, 0, stream>>>(nfn, n4);

    for (int s = 0; s < 4; s++) {
        edge_step_k<<<eblocksS, 256, 0, stream>>>(srcj, tgti, nf0_bf, nf_bf,
                                                  ef0_bf, ef_bf, nfn,
                                                  w0T, meb0, w1T, meb1, wmT, mnb0, E);
        f2bfz_k<<<zgrid, 256, 0, stream>>>(nfn, nf_bf, n4);
    }

    classify_k<<<eblocks32, 256, 0, stream>>>(ef_bf, cw0T, cb0, cw1, cb1, cw2, cb2,
                                              (float*)d_out, E);
}